// Round 8
// baseline (644.624 us; speedup 1.0000x reference)
//
#include <hip/hip_runtime.h>

// SketchDecoder: sequential 1000-step scan, 5-float carried state.
// Ref bug: hidden state never propagated -> W_hh unused, fg gate unused.
// R17 = R15 (473.8us, best) + exec-masked merged tree+write ONLY:
//  - R16 post-mortem: dump-write (all-64-lane stores into one row) pushed
//    bank conflicts 9760->43920 and erased the merge's gain -> dump
//    falsified, merge untested-clean. R17 isolates the merge: per-k
//    {3-level DPP tree -> exec-masked 8-lane ds_write}, so write-k's LDS
//    drain overlaps tree-(k+1) issue; writes stay conflict-free.
// Floor model (stable over R13-R16 audits): trans issue 384cy/step (48
// trans/thread x 8cy, minimal for XLA-bit-exact sigmoid*tanh) + pk-VALU
// ~300 + LDS round trip ~200 + epilogue chain ~200-250 => ~1080-1130cy;
// measured 1142. If R17 is flat we are AT the structural floor.
// RNG: JAX partitionable threefry: bits[i] = o0^o1 of threefry2x32((0,42),(0,i)).

typedef float v2f __attribute__((ext_vector_type(2)));

#define HH   2048
#define MAXS 1000
#define NT   256
#define NWAVE (NT / 64)
#define EPT  4              // v2f pairs per thread (8 floats)

static __device__ __forceinline__ float exp2g(float x){ return __builtin_amdgcn_exp2f(x); }
static __device__ __forceinline__ float rcpg (float x){ return __builtin_amdgcn_rcpf(x); }
static __device__ __forceinline__ v2f exp2v(v2f x){ v2f r; r.x = exp2g(x.x); r.y = exp2g(x.y); return r; }
static __device__ __forceinline__ v2f rcpv (v2f x){ v2f r; r.x = rcpg(x.x); r.y = rcpg(x.y); return r; }

// whole-vector pin: keeps the 64-bit pair intact (no component tearing)
static __device__ __forceinline__ void pin(v2f &v){
  asm volatile("" : "+v"(v));
}

template<int CTRL>
static __device__ __forceinline__ float dpp_add(float x){
  int t = __builtin_amdgcn_update_dpp(0, __builtin_bit_cast(int, x), CTRL, 0xF, 0xF, true);
  return x + __builtin_bit_cast(float, t);
}
template<int CTRL>
static __device__ __forceinline__ float dpp_mov(float x){
  int t = __builtin_amdgcn_update_dpp(0, __builtin_bit_cast(int, x), CTRL, 0xF, 0xF, true);
  return __builtin_bit_cast(float, t);
}
// 3-level shr reduce: lane 7 of each 8-lane group holds the 8-sum
static __device__ __forceinline__ float wave_sum8(float x){
  x = dpp_add<0x111>(x);  // row_shr:1
  x = dpp_add<0x112>(x);  // row_shr:2
  x = dpp_add<0x114>(x);  // row_shr:4
  return x;
}
static __device__ __forceinline__ float rdlane(float x, int l){
  return __builtin_bit_cast(float, __builtin_amdgcn_readlane(__builtin_bit_cast(int, x), l));
}

// ---- JAX threefry2x32, key (0, 42) ----
static __device__ __forceinline__ void tf_round(unsigned &x0, unsigned &x1, const int r){
  x0 += x1;
  x1 = (x1 << r) | (x1 >> (32 - r));
  x1 ^= x0;
}
static __device__ void threefry2x32_0_42(unsigned c0, unsigned c1, unsigned &o0, unsigned &o1){
  const unsigned k0 = 0u, k1 = 42u;
  const unsigned k2 = 0x1BD11BDAu ^ k0 ^ k1;
  unsigned x0 = c0 + k0, x1 = c1 + k1;
  tf_round(x0,x1,13); tf_round(x0,x1,15); tf_round(x0,x1,26); tf_round(x0,x1, 6);
  x0 += k1; x1 += k2 + 1u;
  tf_round(x0,x1,17); tf_round(x0,x1,29); tf_round(x0,x1,16); tf_round(x0,x1,24);
  x0 += k2; x1 += k0 + 2u;
  tf_round(x0,x1,13); tf_round(x0,x1,15); tf_round(x0,x1,26); tf_round(x0,x1, 6);
  x0 += k0; x1 += k1 + 3u;
  tf_round(x0,x1,17); tf_round(x0,x1,29); tf_round(x0,x1,16); tf_round(x0,x1,24);
  x0 += k1; x1 += k2 + 4u;
  tf_round(x0,x1,13); tf_round(x0,x1,15); tf_round(x0,x1,26); tf_round(x0,x1, 6);
  x0 += k2; x1 += k0 + 5u;
  o0 = x0; o1 = x1;
}

// XLA ErfInv32 (Giles polynomial)
static __device__ float erfinv32(float x){
  float w = -log1pf(-x * x);
  float p;
  if (w < 5.0f){
    w -= 2.5f;
    p = 2.81022636e-08f;
    p = fmaf(p, w, 3.43273939e-07f);
    p = fmaf(p, w, -3.5233877e-06f);
    p = fmaf(p, w, -4.39150654e-06f);
    p = fmaf(p, w, 0.00021858087f);
    p = fmaf(p, w, -0.00125372503f);
    p = fmaf(p, w, -0.00417768164f);
    p = fmaf(p, w, 0.246640727f);
    p = fmaf(p, w, 1.50140941f);
  } else {
    w = sqrtf(w) - 3.0f;
    p = -0.000200214257f;
    p = fmaf(p, w, 0.000100950558f);
    p = fmaf(p, w, 0.00134934322f);
    p = fmaf(p, w, -0.00367342844f);
    p = fmaf(p, w, 0.00573950773f);
    p = fmaf(p, w, -0.0076224613f);
    p = fmaf(p, w, 0.00943887047f);
    p = fmaf(p, w, 1.00167406f);
    p = fmaf(p, w, 2.83297682f);
  }
  return p * x;
}

static __device__ float bits_to_normal(unsigned b){
  float f = __builtin_bit_cast(float, (b >> 9) | 0x3f800000u) - 1.0f;
  const float lo = -0x1.fffffep-1f;
  float u = f * (1.0f - lo) + lo;
  u = fmaxf(lo, u);
  return 1.4142135381698608f * erfinv32(u);
}

__global__ __launch_bounds__(NT, 1) void sketch_kernel(
    const float* __restrict__ Wih, const float* __restrict__ bih,
    const float* __restrict__ bhh, const float* __restrict__ Wlin,
    const float* __restrict__ blin, float* __restrict__ out)
{
  __shared__ float2 EPS2[MAXS];
  // [parity][k (7 used, row 7 stays 0)][32 slots + 4 pad words]
  __shared__ __align__(16) float PBuf[2][8][36];

  const int t    = threadIdx.x;
  const int lane = t & 63;
  const int wv   = t >> 6;

  // ---- init output: pad rows [0,0,0,0,1], row 0 = [0,0,1,0,0] ----
  for (int idx = t; idx < 5 * MAXS; idx += NT){
    int c = idx % 5;
    float v = (c == 4) ? 1.0f : 0.0f;
    if (idx == 2) v = 1.0f;
    else if (idx == 4) v = 0.0f;
    out[idx] = v;
  }

  // ---- eps via partitionable threefry; row-major (1000,2) as float2 ----
  for (int e = t; e < MAXS; e += NT){
    unsigned a0, a1, b0, b1;
    threefry2x32_0_42(0u, (unsigned)(2*e),     a0, a1);
    threefry2x32_0_42(0u, (unsigned)(2*e + 1), b0, b1);
    float2 ep; ep.x = bits_to_normal(a0 ^ a1); ep.y = bits_to_normal(b0 ^ b1);
    EPS2[e] = ep;
  }
  for (int idx = t; idx < 2*8*36; idx += NT) ((float*)PBuf)[idx] = 0.0f;

  // ---- preload weights into registers (log2e pre-scaled, p6-eliminated) ----
  // gates(row) = w0*sx + w1*sy + (w2-w4)*p4 + (w3-w4)*p5 + (b + w4)
  const float L2E  = 1.4426950408889634f;
  const float L2E2 = 2.8853900817779268f;
  const int j = t * (2 * EPT);   // 8 h-elements per thread: j..j+7

  v2f wig[EPT][4], wgg[EPT][4], wog[EPT][4];
  v2f big[EPT], bgg[EPT], bog[EPT];
  v2f wl[7][EPT];

  #pragma unroll
  for (int p = 0; p < EPT; p++){
    const int r0 = j + 2*p, r1 = j + 2*p + 1;
    const int gi = 0, gg_ = 2*HH, go = 3*HH;
    float i4x = Wih[(gi+r0)*5 + 4], i4y = Wih[(gi+r1)*5 + 4];
    float g4x = Wih[(gg_+r0)*5 + 4], g4y = Wih[(gg_+r1)*5 + 4];
    float o4x = Wih[(go+r0)*5 + 4], o4y = Wih[(go+r1)*5 + 4];
    #pragma unroll
    for (int c = 0; c < 2; c++){   // sx, sy columns: plain
      v2f a; a.x = Wih[(gi+r0)*5 + c];  a.y = Wih[(gi+r1)*5 + c];  wig[p][c] = a * L2E;
      v2f g; g.x = Wih[(gg_+r0)*5 + c]; g.y = Wih[(gg_+r1)*5 + c]; wgg[p][c] = g * L2E2;
      v2f o; o.x = Wih[(go+r0)*5 + c];  o.y = Wih[(go+r1)*5 + c];  wog[p][c] = o * L2E;
    }
    #pragma unroll
    for (int c = 2; c < 4; c++){   // p4, p5 columns: minus w4
      v2f a; a.x = Wih[(gi+r0)*5 + c] - i4x;  a.y = Wih[(gi+r1)*5 + c] - i4y;  wig[p][c] = a * L2E;
      v2f g; g.x = Wih[(gg_+r0)*5 + c] - g4x; g.y = Wih[(gg_+r1)*5 + c] - g4y; wgg[p][c] = g * L2E2;
      v2f o; o.x = Wih[(go+r0)*5 + c] - o4x;  o.y = Wih[(go+r1)*5 + c] - o4y;  wog[p][c] = o * L2E;
    }
    v2f bi; bi.x = bih[r0] + bhh[r0] + i4x;                 bi.y = bih[r1] + bhh[r1] + i4y;                 big[p] = bi * L2E;
    v2f bg; bg.x = bih[gg_+r0] + bhh[gg_+r0] + g4x;         bg.y = bih[gg_+r1] + bhh[gg_+r1] + g4y;         bgg[p] = bg * L2E2;
    v2f bo; bo.x = bih[go+r0] + bhh[go+r0] + o4x;           bo.y = bih[go+r1] + bhh[go+r1] + o4y;           bog[p] = bo * L2E;
    #pragma unroll
    for (int k = 0; k < 7; k++){
      v2f wk; wk.x = Wlin[k*HH + r0]; wk.y = Wlin[k*HH + r1]; wl[k][p] = wk;
    }
  }

  // pin weights as whole pairs (asm-def: no remat, stays in unified RF)
  #pragma unroll
  for (int p = 0; p < EPT; p++){
    #pragma unroll
    for (int c = 0; c < 4; c++){ pin(wig[p][c]); pin(wgg[p][c]); pin(wog[p][c]); }
    pin(big[p]); pin(bgg[p]); pin(bog[p]);
    #pragma unroll
    for (int k = 0; k < 7; k++) pin(wl[k][p]);
  }

  const int kg = lane >> 3;                       // this lane's k-group (8 lanes/group)
  const float blv = (kg < 7) ? blin[kg] : 0.0f;
  // per-group epilogue transform scale: groups 1,3 -> e^{o/2}; others -> e^{o}
  const float scv = (kg == 1 || kg == 3) ? 0.7213475204444817f : L2E;
  const bool eps_y = (kg == 3);
  const bool slotlane = ((lane & 7) == 7);        // 8 slot lanes per wave
  const int  slot = (wv << 3) + (lane >> 3);      // this slot lane's column

  __syncthreads();

  // carried state (redundant on every lane): last = [0,0,1,0,0] -> (sx,sy,p4,p5)=(0,0,1,0)
  float l0 = 0.f, l1 = 0.f, l2 = 1.f, l3 = 0.f;
  int par = 0;

  for (int i = 1; i < MAXS; i++){
    float2 ep = EPS2[i];                          // prefetch (one b64), waited late

    // ---- gates + h + fused dot-partial accumulation ----
    // dot FMAs of pair p issue in the trans-latency shadow of pair p+1.
    v2f acc[7];
    #pragma unroll
    for (int p = 0; p < EPT; p++){
      v2f ig = big[p] + wig[p][0]*l0 + wig[p][1]*l1 + wig[p][2]*l2 + wig[p][3]*l3;
      v2f gg = bgg[p] + wgg[p][0]*l0 + wgg[p][1]*l1 + wgg[p][2]*l2 + wgg[p][3]*l3;
      v2f og = bog[p] + wog[p][0]*l0 + wog[p][1]*l1 + wog[p][2]*l2 + wog[p][3]*l3;
      v2f a  = exp2v(-ig);                       // e^{-ig}
      v2f b  = exp2v(gg);                        // e^{2*gg}
      v2f r1 = rcpv((1.0f + a) * (1.0f + b));
      v2f st2 = (b * L2E2 - L2E2) * r1;          // c * 2*log2(e)
      v2f d  = exp2v(st2);                       // e^{2c}
      v2f ao = exp2v(-og);                       // e^{-og}
      v2f r2 = rcpv((1.0f + ao) * (1.0f + d));
      v2f h;                                     // sig(og)*tanh(c) = (d-1)*r2
      h.x = fmaf(d.x, r2.x, -r2.x);
      h.y = fmaf(d.y, r2.y, -r2.y);
      if (p == 0){
        #pragma unroll
        for (int k = 0; k < 7; k++) acc[k] = wl[k][0] * h;
      } else {
        #pragma unroll
        for (int k = 0; k < 7; k++) acc[k] = acc[k] + wl[k][p] * h;
      }
    }

    // ---- merged tree+write, exec-masked stores (conflict-free slots):
    //      per k: all-lane 3-level DPP tree, then 8 slot lanes ds_write.
    //      write-k's LDS drain overlaps tree-(k+1) issue. ----
    {
      float* wp = &PBuf[par][0][slot];
      #pragma unroll
      for (int k = 0; k < 7; k++){
        float s = wave_sum8(acc[k].x + acc[k].y);
        if (slotlane) wp[k * 36] = s;            // imm offset k*144B
      }
    }
    __syncthreads();

    // ---- cross-wave: each 8-lane k-group loads its 32 partials (b128/lane),
    //      3 adds + 3-op all-lane butterfly -> every lane holds its k-total ----
    const float4 v4 = *(const float4*)&PBuf[par][kg][(lane & 7) << 2];
    par ^= 1;
    float v = (v4.x + v4.y) + (v4.z + v4.w);
    v = dpp_add<0xB1>(v);    // quad_perm [1,0,3,2]  (^1)
    v = dpp_add<0x4E>(v);    // quad_perm [2,3,0,1]  (^2)
    v = dpp_add<0x141>(v);   // row_half_mirror      (pairs quads within 8)
    float o  = 1.0f - 2.0f * rcpg(1.0f + exp2g((v + blv) * L2E2));   // tanh(dot+b)
    // per-group pre-readlane transforms (bit-identical to per-lane epilogue):
    float tv = exp2g(o * scv);             // g1: sigx, g3: sigy, g4..6: e4..e6
    float od = dpp_mov<0x118>(o);          // row_shr:8 -> g1 gets o0, g3 gets o2
    float sv = fmaf(tv, eps_y ? ep.y : ep.x, od);   // g1: sx, g3: sy
    float sx = rdlane(sv, 8),  sy = rdlane(sv, 24);
    float e4 = rdlane(tv, 32), e5 = rdlane(tv, 40), e6 = rdlane(tv, 48);
    float rs = rcpg(e4 + e5 + e6);         // softmax w/o max-sub (|o|<=1)
    float p4v = e4 * rs, p5v = e5 * rs;
    bool dn = (e6 > e4) && (e6 > e5);      // exp2 monotone: same as o-compare

    if (t < 5){
      float p6v = e6 * rs;
      float val = (t == 0) ? sx : (t == 1) ? sy : (t == 2) ? p4v : (t == 3) ? p5v : p6v;
      out[i*5 + t] = val;
    }
    l0 = sx; l1 = sy; l2 = p4v; l3 = p5v;
    if (dn) break;   // block-uniform: all waves computed identical values
  }
}

extern "C" void kernel_launch(void* const* d_in, const int* in_sizes, int n_in,
                              void* d_out, int out_size, void* d_ws, size_t ws_size,
                              hipStream_t stream) {
  const float* Wih  = (const float*)d_in[0];
  // d_in[1] = W_hh: dead (hidden state never propagated in the reference)
  const float* bih  = (const float*)d_in[2];
  const float* bhh  = (const float*)d_in[3];
  const float* Wlin = (const float*)d_in[4];
  const float* blin = (const float*)d_in[5];
  float* out = (float*)d_out;
  sketch_kernel<<<dim3(1), dim3(NT), 0, stream>>>(Wih, bih, bhh, Wlin, blin, out);
}

// Round 9
// 557.557 us; speedup vs baseline: 1.1562x; 1.1562x over previous
//
#include <hip/hip_runtime.h>

// SketchDecoder: sequential 1000-step scan, 5-float carried state.
// Ref bug: hidden state never propagated -> W_hh unused, fg gate unused.
// R18 = exact revert to R15 (473.8us dispatch — best measured).
//  - R16 (dump-write) falsified: all-64-lane stores into one row -> bank
//    conflicts 9760->43920, +0.4%.
//  - R17 (exec-masked merged tree+write) falsified: 7 exec-mask regions
//    interleaved with DPP trees serialize the scheduler -> +190cy/step
//    stall (busy unchanged at ~690cy), +17%.
// Floor accounting (stable R13-R17): trans issue 384cy/step (2048 elem x 6
// trans / 4 SIMDs x 8cy — config-invariant, fixed by bit-exactness) +
// pk-VALU ~306 = busy 690 (measured); serial segment ~448 (tree tail,
// write drain, barrier, ds_read ~120, butterfly, epilogue chain) resisted
// two targeted attacks. Measured 1138cy/step vs modeled floor ~1080-1130.
// RNG: JAX partitionable threefry: bits[i] = o0^o1 of threefry2x32((0,42),(0,i)).

typedef float v2f __attribute__((ext_vector_type(2)));

#define HH   2048
#define MAXS 1000
#define NT   256
#define NWAVE (NT / 64)
#define EPT  4              // v2f pairs per thread (8 floats)

static __device__ __forceinline__ float exp2g(float x){ return __builtin_amdgcn_exp2f(x); }
static __device__ __forceinline__ float rcpg (float x){ return __builtin_amdgcn_rcpf(x); }
static __device__ __forceinline__ v2f exp2v(v2f x){ v2f r; r.x = exp2g(x.x); r.y = exp2g(x.y); return r; }
static __device__ __forceinline__ v2f rcpv (v2f x){ v2f r; r.x = rcpg(x.x); r.y = rcpg(x.y); return r; }

// whole-vector pin: keeps the 64-bit pair intact (no component tearing)
static __device__ __forceinline__ void pin(v2f &v){
  asm volatile("" : "+v"(v));
}

template<int CTRL>
static __device__ __forceinline__ float dpp_add(float x){
  int t = __builtin_amdgcn_update_dpp(0, __builtin_bit_cast(int, x), CTRL, 0xF, 0xF, true);
  return x + __builtin_bit_cast(float, t);
}
template<int CTRL>
static __device__ __forceinline__ float dpp_mov(float x){
  int t = __builtin_amdgcn_update_dpp(0, __builtin_bit_cast(int, x), CTRL, 0xF, 0xF, true);
  return __builtin_bit_cast(float, t);
}
// 3-level shr reduce: lane 7 of each 8-lane group holds the 8-sum
static __device__ __forceinline__ float wave_sum8(float x){
  x = dpp_add<0x111>(x);  // row_shr:1
  x = dpp_add<0x112>(x);  // row_shr:2
  x = dpp_add<0x114>(x);  // row_shr:4
  return x;
}
static __device__ __forceinline__ float rdlane(float x, int l){
  return __builtin_bit_cast(float, __builtin_amdgcn_readlane(__builtin_bit_cast(int, x), l));
}

// ---- JAX threefry2x32, key (0, 42) ----
static __device__ __forceinline__ void tf_round(unsigned &x0, unsigned &x1, const int r){
  x0 += x1;
  x1 = (x1 << r) | (x1 >> (32 - r));
  x1 ^= x0;
}
static __device__ void threefry2x32_0_42(unsigned c0, unsigned c1, unsigned &o0, unsigned &o1){
  const unsigned k0 = 0u, k1 = 42u;
  const unsigned k2 = 0x1BD11BDAu ^ k0 ^ k1;
  unsigned x0 = c0 + k0, x1 = c1 + k1;
  tf_round(x0,x1,13); tf_round(x0,x1,15); tf_round(x0,x1,26); tf_round(x0,x1, 6);
  x0 += k1; x1 += k2 + 1u;
  tf_round(x0,x1,17); tf_round(x0,x1,29); tf_round(x0,x1,16); tf_round(x0,x1,24);
  x0 += k2; x1 += k0 + 2u;
  tf_round(x0,x1,13); tf_round(x0,x1,15); tf_round(x0,x1,26); tf_round(x0,x1, 6);
  x0 += k0; x1 += k1 + 3u;
  tf_round(x0,x1,17); tf_round(x0,x1,29); tf_round(x0,x1,16); tf_round(x0,x1,24);
  x0 += k1; x1 += k2 + 4u;
  tf_round(x0,x1,13); tf_round(x0,x1,15); tf_round(x0,x1,26); tf_round(x0,x1, 6);
  x0 += k2; x1 += k0 + 5u;
  o0 = x0; o1 = x1;
}

// XLA ErfInv32 (Giles polynomial)
static __device__ float erfinv32(float x){
  float w = -log1pf(-x * x);
  float p;
  if (w < 5.0f){
    w -= 2.5f;
    p = 2.81022636e-08f;
    p = fmaf(p, w, 3.43273939e-07f);
    p = fmaf(p, w, -3.5233877e-06f);
    p = fmaf(p, w, -4.39150654e-06f);
    p = fmaf(p, w, 0.00021858087f);
    p = fmaf(p, w, -0.00125372503f);
    p = fmaf(p, w, -0.00417768164f);
    p = fmaf(p, w, 0.246640727f);
    p = fmaf(p, w, 1.50140941f);
  } else {
    w = sqrtf(w) - 3.0f;
    p = -0.000200214257f;
    p = fmaf(p, w, 0.000100950558f);
    p = fmaf(p, w, 0.00134934322f);
    p = fmaf(p, w, -0.00367342844f);
    p = fmaf(p, w, 0.00573950773f);
    p = fmaf(p, w, -0.0076224613f);
    p = fmaf(p, w, 0.00943887047f);
    p = fmaf(p, w, 1.00167406f);
    p = fmaf(p, w, 2.83297682f);
  }
  return p * x;
}

static __device__ float bits_to_normal(unsigned b){
  float f = __builtin_bit_cast(float, (b >> 9) | 0x3f800000u) - 1.0f;
  const float lo = -0x1.fffffep-1f;
  float u = f * (1.0f - lo) + lo;
  u = fmaxf(lo, u);
  return 1.4142135381698608f * erfinv32(u);
}

__global__ __launch_bounds__(NT, 1) void sketch_kernel(
    const float* __restrict__ Wih, const float* __restrict__ bih,
    const float* __restrict__ bhh, const float* __restrict__ Wlin,
    const float* __restrict__ blin, float* __restrict__ out)
{
  __shared__ float2 EPS2[MAXS];
  // [parity][k (7 used, row 7 stays 0)][32 slots + 4 pad words]
  __shared__ __align__(16) float PBuf[2][8][36];

  const int t    = threadIdx.x;
  const int lane = t & 63;
  const int wv   = t >> 6;

  // ---- init output: pad rows [0,0,0,0,1], row 0 = [0,0,1,0,0] ----
  for (int idx = t; idx < 5 * MAXS; idx += NT){
    int c = idx % 5;
    float v = (c == 4) ? 1.0f : 0.0f;
    if (idx == 2) v = 1.0f;
    else if (idx == 4) v = 0.0f;
    out[idx] = v;
  }

  // ---- eps via partitionable threefry; row-major (1000,2) as float2 ----
  for (int e = t; e < MAXS; e += NT){
    unsigned a0, a1, b0, b1;
    threefry2x32_0_42(0u, (unsigned)(2*e),     a0, a1);
    threefry2x32_0_42(0u, (unsigned)(2*e + 1), b0, b1);
    float2 ep; ep.x = bits_to_normal(a0 ^ a1); ep.y = bits_to_normal(b0 ^ b1);
    EPS2[e] = ep;
  }
  for (int idx = t; idx < 2*8*36; idx += NT) ((float*)PBuf)[idx] = 0.0f;

  // ---- preload weights into registers (log2e pre-scaled, p6-eliminated) ----
  // gates(row) = w0*sx + w1*sy + (w2-w4)*p4 + (w3-w4)*p5 + (b + w4)
  const float L2E  = 1.4426950408889634f;
  const float L2E2 = 2.8853900817779268f;
  const int j = t * (2 * EPT);   // 8 h-elements per thread: j..j+7

  v2f wig[EPT][4], wgg[EPT][4], wog[EPT][4];
  v2f big[EPT], bgg[EPT], bog[EPT];
  v2f wl[7][EPT];

  #pragma unroll
  for (int p = 0; p < EPT; p++){
    const int r0 = j + 2*p, r1 = j + 2*p + 1;
    const int gi = 0, gg_ = 2*HH, go = 3*HH;
    float i4x = Wih[(gi+r0)*5 + 4], i4y = Wih[(gi+r1)*5 + 4];
    float g4x = Wih[(gg_+r0)*5 + 4], g4y = Wih[(gg_+r1)*5 + 4];
    float o4x = Wih[(go+r0)*5 + 4], o4y = Wih[(go+r1)*5 + 4];
    #pragma unroll
    for (int c = 0; c < 2; c++){   // sx, sy columns: plain
      v2f a; a.x = Wih[(gi+r0)*5 + c];  a.y = Wih[(gi+r1)*5 + c];  wig[p][c] = a * L2E;
      v2f g; g.x = Wih[(gg_+r0)*5 + c]; g.y = Wih[(gg_+r1)*5 + c]; wgg[p][c] = g * L2E2;
      v2f o; o.x = Wih[(go+r0)*5 + c];  o.y = Wih[(go+r1)*5 + c];  wog[p][c] = o * L2E;
    }
    #pragma unroll
    for (int c = 2; c < 4; c++){   // p4, p5 columns: minus w4
      v2f a; a.x = Wih[(gi+r0)*5 + c] - i4x;  a.y = Wih[(gi+r1)*5 + c] - i4y;  wig[p][c] = a * L2E;
      v2f g; g.x = Wih[(gg_+r0)*5 + c] - g4x; g.y = Wih[(gg_+r1)*5 + c] - g4y; wgg[p][c] = g * L2E2;
      v2f o; o.x = Wih[(go+r0)*5 + c] - o4x;  o.y = Wih[(go+r1)*5 + c] - o4y;  wog[p][c] = o * L2E;
    }
    v2f bi; bi.x = bih[r0] + bhh[r0] + i4x;                 bi.y = bih[r1] + bhh[r1] + i4y;                 big[p] = bi * L2E;
    v2f bg; bg.x = bih[gg_+r0] + bhh[gg_+r0] + g4x;         bg.y = bih[gg_+r1] + bhh[gg_+r1] + g4y;         bgg[p] = bg * L2E2;
    v2f bo; bo.x = bih[go+r0] + bhh[go+r0] + o4x;           bo.y = bih[go+r1] + bhh[go+r1] + o4y;           bog[p] = bo * L2E;
    #pragma unroll
    for (int k = 0; k < 7; k++){
      v2f wk; wk.x = Wlin[k*HH + r0]; wk.y = Wlin[k*HH + r1]; wl[k][p] = wk;
    }
  }

  // pin weights as whole pairs (asm-def: no remat, stays in unified RF)
  #pragma unroll
  for (int p = 0; p < EPT; p++){
    #pragma unroll
    for (int c = 0; c < 4; c++){ pin(wig[p][c]); pin(wgg[p][c]); pin(wog[p][c]); }
    pin(big[p]); pin(bgg[p]); pin(bog[p]);
    #pragma unroll
    for (int k = 0; k < 7; k++) pin(wl[k][p]);
  }

  const int kg = lane >> 3;                       // this lane's k-group (8 lanes/group)
  const float blv = (kg < 7) ? blin[kg] : 0.0f;
  // per-group epilogue transform scale: groups 1,3 -> e^{o/2}; others -> e^{o}
  const float scv = (kg == 1 || kg == 3) ? 0.7213475204444817f : L2E;
  const bool eps_y = (kg == 3);

  __syncthreads();

  // carried state (redundant on every lane): last = [0,0,1,0,0] -> (sx,sy,p4,p5)=(0,0,1,0)
  float l0 = 0.f, l1 = 0.f, l2 = 1.f, l3 = 0.f;
  int par = 0;

  for (int i = 1; i < MAXS; i++){
    float2 ep = EPS2[i];                          // prefetch (one b64), waited late

    // ---- gates + h + fused dot-partial accumulation ----
    // dot FMAs of pair p issue in the trans-latency shadow of pair p+1.
    v2f acc[7];
    #pragma unroll
    for (int p = 0; p < EPT; p++){
      v2f ig = big[p] + wig[p][0]*l0 + wig[p][1]*l1 + wig[p][2]*l2 + wig[p][3]*l3;
      v2f gg = bgg[p] + wgg[p][0]*l0 + wgg[p][1]*l1 + wgg[p][2]*l2 + wgg[p][3]*l3;
      v2f og = bog[p] + wog[p][0]*l0 + wog[p][1]*l1 + wog[p][2]*l2 + wog[p][3]*l3;
      v2f a  = exp2v(-ig);                       // e^{-ig}
      v2f b  = exp2v(gg);                        // e^{2*gg}
      v2f r1 = rcpv((1.0f + a) * (1.0f + b));
      v2f st2 = (b * L2E2 - L2E2) * r1;          // c * 2*log2(e)
      v2f d  = exp2v(st2);                       // e^{2c}
      v2f ao = exp2v(-og);                       // e^{-og}
      v2f r2 = rcpv((1.0f + ao) * (1.0f + d));
      v2f h;                                     // sig(og)*tanh(c) = (d-1)*r2
      h.x = fmaf(d.x, r2.x, -r2.x);
      h.y = fmaf(d.y, r2.y, -r2.y);
      if (p == 0){
        #pragma unroll
        for (int k = 0; k < 7; k++) acc[k] = wl[k][0] * h;
      } else {
        #pragma unroll
        for (int k = 0; k < 7; k++) acc[k] = acc[k] + wl[k][p] * h;
      }
    }

    // ---- 3-level DPP reduce (8-sums); 8 lanes/wave store 8 partials/k ----
    float sarr[7];
    #pragma unroll
    for (int k = 0; k < 7; k++){
      sarr[k] = wave_sum8(acc[k].x + acc[k].y);
    }
    if ((lane & 7) == 7){
      float* bp = &PBuf[par][0][(wv << 3) + (lane >> 3)];
      #pragma unroll
      for (int k = 0; k < 7; k++) bp[k * 36] = sarr[k];
    }
    __syncthreads();

    // ---- cross-wave: each 8-lane k-group loads its 32 partials (b128/lane),
    //      3 adds + 3-op all-lane butterfly -> every lane holds its k-total ----
    const float4 v4 = *(const float4*)&PBuf[par][kg][(lane & 7) << 2];
    par ^= 1;
    float v = (v4.x + v4.y) + (v4.z + v4.w);
    v = dpp_add<0xB1>(v);    // quad_perm [1,0,3,2]  (^1)
    v = dpp_add<0x4E>(v);    // quad_perm [2,3,0,1]  (^2)
    v = dpp_add<0x141>(v);   // row_half_mirror      (pairs quads within 8)
    float o  = 1.0f - 2.0f * rcpg(1.0f + exp2g((v + blv) * L2E2));   // tanh(dot+b)
    // per-group pre-readlane transforms (bit-identical to per-lane epilogue):
    float tv = exp2g(o * scv);             // g1: sigx, g3: sigy, g4..6: e4..e6
    float od = dpp_mov<0x118>(o);          // row_shr:8 -> g1 gets o0, g3 gets o2
    float sv = fmaf(tv, eps_y ? ep.y : ep.x, od);   // g1: sx, g3: sy
    float sx = rdlane(sv, 8),  sy = rdlane(sv, 24);
    float e4 = rdlane(tv, 32), e5 = rdlane(tv, 40), e6 = rdlane(tv, 48);
    float rs = rcpg(e4 + e5 + e6);         // softmax w/o max-sub (|o|<=1)
    float p4v = e4 * rs, p5v = e5 * rs;
    bool dn = (e6 > e4) && (e6 > e5);      // exp2 monotone: same as o-compare

    if (t < 5){
      float p6v = e6 * rs;
      float val = (t == 0) ? sx : (t == 1) ? sy : (t == 2) ? p4v : (t == 3) ? p5v : p6v;
      out[i*5 + t] = val;
    }
    l0 = sx; l1 = sy; l2 = p4v; l3 = p5v;
    if (dn) break;   // block-uniform: all waves computed identical values
  }
}

extern "C" void kernel_launch(void* const* d_in, const int* in_sizes, int n_in,
                              void* d_out, int out_size, void* d_ws, size_t ws_size,
                              hipStream_t stream) {
  const float* Wih  = (const float*)d_in[0];
  // d_in[1] = W_hh: dead (hidden state never propagated in the reference)
  const float* bih  = (const float*)d_in[2];
  const float* bhh  = (const float*)d_in[3];
  const float* Wlin = (const float*)d_in[4];
  const float* blin = (const float*)d_in[5];
  float* out = (float*)d_out;
  sketch_kernel<<<dim3(1), dim3(NT), 0, stream>>>(Wih, bih, bhh, Wlin, blin, out);
}